// Round 16
// baseline (404.867 us; speedup 1.0000x reference)
//
#include <hip/hip_runtime.h>
#include <hip/hip_bf16.h>

#define BN_EPS 1e-5f

typedef __attribute__((ext_vector_type(8))) short short8;
typedef __attribute__((ext_vector_type(4))) float f32x4;

__device__ __forceinline__ void gll16(const void* g, void* l) {
    __builtin_amdgcn_global_load_lds(
        (const __attribute__((address_space(1))) unsigned int*)g,
        (__attribute__((address_space(3))) unsigned int*)l, 16, 0, 0);
}

__device__ __forceinline__ unsigned pack_bf2(float a, float b) {
    __hip_bfloat16 ba = __float2bfloat16(a);
    __hip_bfloat16 bb = __float2bfloat16(b);
    return (unsigned)(*(unsigned short*)&ba) | ((unsigned)(*(unsigned short*)&bb) << 16);
}

// ===========================================================================
// CSR construction (graph identical across the 3 layers)
// ===========================================================================
__global__ void hist_kernel(const int* __restrict__ dst, int* __restrict__ off, int E) {
    int e = blockIdx.x * blockDim.x + threadIdx.x;
    if (e < E) atomicAdd(&off[dst[e] + 1], 1);
}

__global__ __launch_bounds__(256) void scan1_kernel(int* __restrict__ data,
                                                    int* __restrict__ sums, int n) {
    __shared__ int sh[256];
    const int t = threadIdx.x;
    const int idx = blockIdx.x * 1024 + t * 4;
    int v[4];
    int s = 0;
#pragma unroll
    for (int j = 0; j < 4; ++j) {
        int x = (idx + j < n) ? data[idx + j] : 0;
        s += x;
        v[j] = s;
    }
    sh[t] = s;
    __syncthreads();
    for (int o = 1; o < 256; o <<= 1) {
        int x = (t >= o) ? sh[t - o] : 0;
        __syncthreads();
        sh[t] += x;
        __syncthreads();
    }
    const int prev = sh[t] - s;
#pragma unroll
    for (int j = 0; j < 4; ++j) {
        if (idx + j < n) data[idx + j] = v[j] + prev;
    }
    if (t == 255) sums[blockIdx.x] = sh[255];
}

__global__ __launch_bounds__(256) void scan2_kernel(int* __restrict__ sums, int nb) {
    __shared__ int sh[256];
    const int t = threadIdx.x;
    sh[t] = (t < nb) ? sums[t] : 0;
    __syncthreads();
    for (int o = 1; o < 256; o <<= 1) {
        int x = (t >= o) ? sh[t - o] : 0;
        __syncthreads();
        sh[t] += x;
        __syncthreads();
    }
    if (t < nb) sums[t] = sh[t];
}

__global__ void scan3_kernel(int* __restrict__ data, const int* __restrict__ sums,
                             int* __restrict__ cursor, int n, int N) {
    int i = blockIdx.x * blockDim.x + threadIdx.x;
    if (i >= n) return;
    int b = i >> 10;
    int v = data[i];
    if (b > 0) { v += sums[b - 1]; data[i] = v; }
    if (i < N) cursor[i] = v;
}

__global__ void fill_kernel(const int* __restrict__ src, const int* __restrict__ dst,
                            int* __restrict__ cursor, int* __restrict__ sorted_src, int E) {
    int e = blockIdx.x * blockDim.x + threadIdx.x;
    if (e >= E) return;
    int p = atomicAdd(&cursor[dst[e]], 1);
    sorted_src[p] = src[e];
}

// ===========================================================================
// prep kernels
// ===========================================================================
__global__ void cvt_x_kernel(const float* __restrict__ x, __hip_bfloat16* __restrict__ xb,
                             int N, int total4 /* Npad*128/4 */) {
    int i = blockIdx.x * blockDim.x + threadIdx.x;
    if (i >= total4) return;
    int n = i >> 5;
    unsigned lo = 0, hi = 0;
    if (n < N) {
        const float4 v = ((const float4*)x)[i];
        lo = pack_bf2(v.x, v.y);
        hi = pack_bf2(v.z, v.w);
    }
    ((uint2*)xb)[i] = make_uint2(lo, hi);
}

__global__ void wt_all_kernel(const float* __restrict__ w0, const float* __restrict__ w1,
                              const float* __restrict__ w2, const float* __restrict__ w3,
                              const float* __restrict__ w4, const float* __restrict__ w5,
                              __hip_bfloat16* __restrict__ o0, __hip_bfloat16* __restrict__ o1,
                              __hip_bfloat16* __restrict__ o2, __hip_bfloat16* __restrict__ o3,
                              __hip_bfloat16* __restrict__ o4, __hip_bfloat16* __restrict__ o5) {
    int i = blockIdx.x * blockDim.x + threadIdx.x;
    const int S0 = 256 * 128, S = 256 * 256;
    if (i < S0) {
        int m = i / 128, k = i - m * 128;
        o0[i] = __float2bfloat16(w0[k * 256 + m]);
        return;
    }
    i -= S0;
    int mi = i / S, j = i - mi * S;
    if (mi >= 5) return;
    int m = j >> 8, k = j & 255;
    const float* Wp; __hip_bfloat16* Op;
    switch (mi) {
        case 0: Wp = w1; Op = o1; break;
        case 1: Wp = w2; Op = o2; break;
        case 2: Wp = w3; Op = o3; break;
        case 3: Wp = w4; Op = o4; break;
        default: Wp = w5; Op = o5; break;
    }
    Op[j] = __float2bfloat16(Wp[k * 256 + m]);
}

__global__ void prep_ss_kernel(
    const float* __restrict__ g0, const float* __restrict__ be0, const float* __restrict__ m0,
    const float* __restrict__ v0, const float* __restrict__ b10, const float* __restrict__ b20,
    const float* __restrict__ g1, const float* __restrict__ be1, const float* __restrict__ m1,
    const float* __restrict__ v1, const float* __restrict__ b11, const float* __restrict__ b21,
    const float* __restrict__ g2, const float* __restrict__ be2, const float* __restrict__ m2,
    const float* __restrict__ v2, const float* __restrict__ b12, const float* __restrict__ b22,
    float* __restrict__ ss) {
    const int layer = blockIdx.x;
    const int c = threadIdx.x;
    const float *g, *be, *m, *v, *b1, *b2;
    switch (layer) {
        case 0: g = g0; be = be0; m = m0; v = v0; b1 = b10; b2 = b20; break;
        case 1: g = g1; be = be1; m = m1; v = v1; b1 = b11; b2 = b21; break;
        default: g = g2; be = be2; m = m2; v = v2; b1 = b12; b2 = b22; break;
    }
    float r = rsqrtf(v[c] + BN_EPS);
    float s = g[c] * r;
    ss[(2 * layer) * 512 + c] = s;
    ss[(2 * layer) * 512 + 256 + c] = (b1[c] - m[c]) * s + be[c];
    ss[(2 * layer + 1) * 512 + c] = 1.f;
    ss[(2 * layer + 1) * 512 + 256 + c] = b2[c];
}

// ===========================================================================
// fused aggregate: out[n] = h[n] + sum_{e in CSR(n)} h[src[e]]  (bf16 in/out)
// 4-deep edge unroll: more gather loads in flight per wave.
// ===========================================================================
template <int C>
__global__ __launch_bounds__(256) void agg_fused(const __hip_bfloat16* __restrict__ h,
                                                 const int* __restrict__ off,
                                                 const int* __restrict__ ssrc,
                                                 __hip_bfloat16* __restrict__ out, int N) {
    constexpr int L = C / 8;
    int t = blockIdx.x * blockDim.x + threadIdx.x;
    int n = t / L;
    if (n >= N) return;
    int c8 = t - n * L;
    const uint4* hp = (const uint4*)h;

    float acc[8];
    {
        uint4 sv = hp[(size_t)n * L + c8];
        const unsigned u[4] = {sv.x, sv.y, sv.z, sv.w};
#pragma unroll
        for (int j = 0; j < 4; ++j) {
            acc[2 * j]     = __uint_as_float(u[j] << 16);
            acc[2 * j + 1] = __uint_as_float(u[j] & 0xffff0000u);
        }
    }
    const int e0 = off[n], e1 = off[n + 1];
    int e = e0;
    for (; e + 4 <= e1; e += 4) {
        int s0 = ssrc[e], s1 = ssrc[e + 1], s2 = ssrc[e + 2], s3 = ssrc[e + 3];
        uint4 a = hp[(size_t)s0 * L + c8];
        uint4 b = hp[(size_t)s1 * L + c8];
        uint4 cc = hp[(size_t)s2 * L + c8];
        uint4 d = hp[(size_t)s3 * L + c8];
        const unsigned ua[4] = {a.x, a.y, a.z, a.w};
        const unsigned ub[4] = {b.x, b.y, b.z, b.w};
        const unsigned uc[4] = {cc.x, cc.y, cc.z, cc.w};
        const unsigned ud[4] = {d.x, d.y, d.z, d.w};
#pragma unroll
        for (int j = 0; j < 4; ++j) {
            acc[2 * j]     += __uint_as_float(ua[j] << 16) + __uint_as_float(ub[j] << 16) +
                              __uint_as_float(uc[j] << 16) + __uint_as_float(ud[j] << 16);
            acc[2 * j + 1] += __uint_as_float(ua[j] & 0xffff0000u) + __uint_as_float(ub[j] & 0xffff0000u) +
                              __uint_as_float(uc[j] & 0xffff0000u) + __uint_as_float(ud[j] & 0xffff0000u);
        }
    }
    for (; e + 2 <= e1; e += 2) {
        int s0 = ssrc[e], s1 = ssrc[e + 1];
        uint4 a = hp[(size_t)s0 * L + c8];
        uint4 b = hp[(size_t)s1 * L + c8];
        const unsigned ua[4] = {a.x, a.y, a.z, a.w};
        const unsigned ub[4] = {b.x, b.y, b.z, b.w};
#pragma unroll
        for (int j = 0; j < 4; ++j) {
            acc[2 * j]     += __uint_as_float(ua[j] << 16) + __uint_as_float(ub[j] << 16);
            acc[2 * j + 1] += __uint_as_float(ua[j] & 0xffff0000u) + __uint_as_float(ub[j] & 0xffff0000u);
        }
    }
    if (e < e1) {
        int s0 = ssrc[e];
        uint4 a = hp[(size_t)s0 * L + c8];
        const unsigned ua[4] = {a.x, a.y, a.z, a.w};
#pragma unroll
        for (int j = 0; j < 4; ++j) {
            acc[2 * j]     += __uint_as_float(ua[j] << 16);
            acc[2 * j + 1] += __uint_as_float(ua[j] & 0xffff0000u);
        }
    }
    unsigned o[4];
#pragma unroll
    for (int j = 0; j < 4; ++j) o[j] = pack_bf2(acc[2 * j], acc[2 * j + 1]);
    ((uint4*)out)[(size_t)n * L + c8] = make_uint4(o[0], o[1], o[2], o[3]);
}

// ===========================================================================
// fused MLP layer (r12/r15 structure): 128-row panel x 256 cols, 8 waves.
// Frag-order 64KB LDS (conflict-clean).
// KEY CHANGE vs r15: 4-DEEP NAMED-SET W register pipeline (wpa..wpd, no
// copies). The r12 2-deep pipeline's per-tile `wc = wn` copy forced a
// `s_waitcnt vmcnt(0)` EVERY tile (full L2 latency exposed 16x/block, the
// T4 "never drain to 0" anti-pattern). Named sets reloaded after
// consumption give ~3 tiles (~300+cyc) of slack -> effective vmcnt(6).
// POOL=true (last layer): in-LDS segmented pooling + atomics (r15).
// ===========================================================================
template <int K1, bool POOL>
__global__ __launch_bounds__(512, 4) void mlp_fused(
    const __hip_bfloat16* __restrict__ A,
    const __hip_bfloat16* __restrict__ W1t,   // [256][K1] bf16 (W1 transposed)
    const __hip_bfloat16* __restrict__ W2t,   // [256][256] bf16
    const float* __restrict__ ss1, const float* __restrict__ ss2,
    __hip_bfloat16* __restrict__ C,
    const int* __restrict__ batch, float* __restrict__ pooled, int N) {
    __shared__ __align__(16) char bufT[64 * 1024];
    __shared__ int batch_sh[128];

    const int tid = threadIdx.x;
    const int l   = tid & 63;
    const int w   = tid >> 6;        // wave 0..7 -> cols w*32..+31
    const int l15 = l & 15;
    const int kg  = l >> 4;          // k-octet group 0..3
    const size_t row0 = (size_t)blockIdx.x * 128;

    constexpr int ROWB = K1 * 2;
    constexpr int NT1  = K1 / 32;    // 4 (K=128) or 8 (K=256)

    const char* W1base = (const char*)W1t + (size_t)(w * 32 + l15) * ROWB + kg * 16;
    const char* W2base = (const char*)W2t + (size_t)(w * 32 + l15) * 512 + kg * 16;

    // ---- 4-deep W pipeline: named sets, compile-time indexed (rule #20) ----
    short8 wpa[2], wpb[2], wpc[2], wpd[2];
    auto loadW1 = [&](short8* d, int t) {
        d[0] = *(const short8*)(W1base + t * 64);
        d[1] = *(const short8*)(W1base + 16 * ROWB + t * 64);
    };
    auto loadW2 = [&](short8* d, int t) {
        d[0] = *(const short8*)(W2base + t * 64);
        d[1] = *(const short8*)(W2base + 16 * 512 + t * 64);
    };

    // W1 tiles 0..3 in flight during A staging
    loadW1(wpa, 0); loadW1(wpb, 1); loadW1(wpc, 2); loadW1(wpd, 3);

    // ---- stage A panel in fragment order ----
    {
        const char* Ab = (const char*)(A + row0 * K1);
#pragma unroll
        for (int ib = w; ib < 8 * NT1; ib += 8) {
            const int j = ib / NT1, t = ib % NT1;
            gll16(Ab + (size_t)(j * 16 + l15) * ROWB + t * 64 + kg * 16,
                  bufT + ib * 1024);
        }
    }
    asm volatile("s_waitcnt vmcnt(0)" ::: "memory");
    __syncthreads();

    f32x4 acc[2][8];
#pragma unroll
    for (int i = 0; i < 2; ++i)
#pragma unroll
        for (int j = 0; j < 8; ++j) acc[i][j] = (f32x4){0.f, 0.f, 0.f, 0.f};

    // ================= GEMM1: T = A @ W1 (4-deep W pipeline) ================
    {
        auto step = [&](int t, const short8* wf) {
#pragma unroll
            for (int jh = 0; jh < 2; ++jh) {
                short8 af[4];
#pragma unroll
                for (int jj = 0; jj < 4; ++jj)
                    af[jj] = *(const short8*)(bufT + ((jh * 4 + jj) * NT1 + t) * 1024 + l * 16);
#pragma unroll
                for (int jj = 0; jj < 4; ++jj) {
                    acc[0][jh * 4 + jj] = __builtin_amdgcn_mfma_f32_16x16x32_bf16(
                        wf[0], af[jj], acc[0][jh * 4 + jj], 0, 0, 0);
                    acc[1][jh * 4 + jj] = __builtin_amdgcn_mfma_f32_16x16x32_bf16(
                        wf[1], af[jj], acc[1][jh * 4 + jj], 0, 0, 0);
                }
            }
        };
#pragma unroll 1
        for (int t = 0; t < NT1; t += 4) {
            step(t + 0, wpa); if (t + 4 < NT1) loadW1(wpa, t + 4);
            step(t + 1, wpb); if (t + 5 < NT1) loadW1(wpb, t + 5);
            step(t + 2, wpc); if (t + 6 < NT1) loadW1(wpc, t + 6);
            step(t + 3, wpd); if (t + 7 < NT1) loadW1(wpd, t + 7);
        }
    }
    __syncthreads();

    // ---- W2 tiles 0..3 in flight during T epilogue ----
    loadW2(wpa, 0); loadW2(wpb, 1); loadW2(wpc, 2); loadW2(wpd, 3);

    // ---- T epilogue: bn+relu, fragment-order packed 8B writes ----
#pragma unroll
    for (int i = 0; i < 2; ++i) {
        const int m0 = w * 32 + i * 16 + kg * 4;
        const float4 s4 = *(const float4*)(ss1 + m0);
        const float4 h4 = *(const float4*)(ss1 + 256 + m0);
        const int toff = w * 1024 + (i * 2 + (kg >> 1)) * 256 + l15 * 16 + (kg & 1) * 8;
#pragma unroll
        for (int j = 0; j < 8; ++j) {
            const float v0 = fmaxf(acc[i][j][0] * s4.x + h4.x, 0.f);
            const float v1 = fmaxf(acc[i][j][1] * s4.y + h4.y, 0.f);
            const float v2 = fmaxf(acc[i][j][2] * s4.z + h4.z, 0.f);
            const float v3 = fmaxf(acc[i][j][3] * s4.w + h4.w, 0.f);
            *(uint2*)(bufT + j * 8192 + toff) = make_uint2(pack_bf2(v0, v1), pack_bf2(v2, v3));
        }
    }
    __syncthreads();

#pragma unroll
    for (int i = 0; i < 2; ++i)
#pragma unroll
        for (int j = 0; j < 8; ++j) acc[i][j] = (f32x4){0.f, 0.f, 0.f, 0.f};

    // ================= GEMM2: C = T @ W2 (4-deep W pipeline) ================
    {
        auto step = [&](int t, const short8* wf) {
#pragma unroll
            for (int jh = 0; jh < 2; ++jh) {
                short8 tf[4];
#pragma unroll
                for (int jj = 0; jj < 4; ++jj)
                    tf[jj] = *(const short8*)(bufT + ((jh * 4 + jj) * 8 + t) * 1024 + l * 16);
#pragma unroll
                for (int jj = 0; jj < 4; ++jj) {
                    acc[0][jh * 4 + jj] = __builtin_amdgcn_mfma_f32_16x16x32_bf16(
                        wf[0], tf[jj], acc[0][jh * 4 + jj], 0, 0, 0);
                    acc[1][jh * 4 + jj] = __builtin_amdgcn_mfma_f32_16x16x32_bf16(
                        wf[1], tf[jj], acc[1][jh * 4 + jj], 0, 0, 0);
                }
            }
        };
#pragma unroll 1
        for (int t = 0; t < 8; t += 4) {
            step(t + 0, wpa); if (t + 4 < 8) loadW2(wpa, t + 4);
            step(t + 1, wpb); if (t + 5 < 8) loadW2(wpb, t + 5);
            step(t + 2, wpc); if (t + 6 < 8) loadW2(wpc, t + 6);
            step(t + 3, wpd); if (t + 7 < 8) loadW2(wpd, t + 7);
        }
    }
    __syncthreads();

    // ---- C epilogue into LDS (fragment order) ----
#pragma unroll
    for (int i = 0; i < 2; ++i) {
        const int c0 = w * 32 + i * 16 + kg * 4;
        const float4 s4 = *(const float4*)(ss2 + c0);
        const float4 h4 = *(const float4*)(ss2 + 256 + c0);
        const int toff = w * 1024 + (i * 2 + (kg >> 1)) * 256 + l15 * 16 + (kg & 1) * 8;
#pragma unroll
        for (int j = 0; j < 8; ++j) {
            const float v0 = fmaxf(acc[i][j][0] * s4.x + h4.x, 0.f);
            const float v1 = fmaxf(acc[i][j][1] * s4.y + h4.y, 0.f);
            const float v2 = fmaxf(acc[i][j][2] * s4.z + h4.z, 0.f);
            const float v3 = fmaxf(acc[i][j][3] * s4.w + h4.w, 0.f);
            *(uint2*)(bufT + j * 8192 + toff) = make_uint2(pack_bf2(v0, v1), pack_bf2(v2, v3));
        }
    }
    if (POOL && tid < 128) {
        const int r = (int)row0 + tid;
        batch_sh[tid] = (r < N) ? batch[r] : -1;
    }
    __syncthreads();

    if (!POOL) {
        char* Cb = (char*)C + row0 * 512;
#pragma unroll
        for (int q = tid; q < 4096; q += 512) {
            const int j  = q >> 9;
            const int wp = (q >> 6) & 7;
            const int lp = q & 63;
            uint4 v = *(const uint4*)(bufT + q * 16);
            *(uint4*)(Cb + (size_t)(j * 16 + (lp & 15)) * 512 + wp * 64 + (lp >> 4) * 16) = v;
        }
    } else {
        // ---- in-LDS segmented pooling: thread = (column, row-half) ----
        const int c  = tid & 255;
        const int rh = tid >> 8;
        const int cbase = (c >> 5) * 1024 +
                          (((c >> 4) & 1) * 2 + ((c >> 3) & 1)) * 256 +
                          ((c >> 2) & 1) * 8 + (c & 3) * 2;
        float accp = 0.f;
        int gprev = -1;
        for (int nn = rh * 64; nn < rh * 64 + 64; ++nn) {
            const int g = batch_sh[nn];
            if (g < 0) break;
            if (g != gprev) {
                if (gprev >= 0) atomicAdd(&pooled[(size_t)gprev * 256 + c], accp);
                accp = 0.f;
                gprev = g;
            }
            const unsigned short* p =
                (const unsigned short*)(bufT + (nn >> 4) * 8192 + cbase + (nn & 15) * 16);
            accp += __uint_as_float(((unsigned)*p) << 16);
        }
        if (gprev >= 0) atomicAdd(&pooled[(size_t)gprev * 256 + c], accp);
    }
}

// ===========================================================================
// head: out[g] = relu(bn(pooled[g]@w0 + b0)) @ w1 + b1
// ===========================================================================
__global__ __launch_bounds__(128) void head_kernel(
    const float* __restrict__ pooled,
    const float* __restrict__ w0, const float* __restrict__ b0,
    const float* __restrict__ g, const float* __restrict__ be,
    const float* __restrict__ m, const float* __restrict__ v,
    const float* __restrict__ w1, const float* __restrict__ b1,
    float* __restrict__ out) {
    __shared__ float row[256];
    __shared__ float red[128];
    const int gid = blockIdx.x;
    const int j = threadIdx.x;

    row[j]       = pooled[(size_t)gid * 256 + j];
    row[j + 128] = pooled[(size_t)gid * 256 + 128 + j];
    __syncthreads();

    float acc = b0[j];
#pragma unroll 8
    for (int k = 0; k < 256; ++k) acc += row[k] * w0[k * 128 + j];

    float h = g[j] * (acc - m[j]) * rsqrtf(v[j] + BN_EPS) + be[j];
    h = fmaxf(h, 0.f) * w1[j];
    red[j] = h;
    __syncthreads();
    for (int s = 64; s > 0; s >>= 1) {
        if (j < s) red[j] += red[j + s];
        __syncthreads();
    }
    if (j == 0) out[gid] = red[0] + b1[0];
}

// ===========================================================================
// launch
// ===========================================================================
extern "C" void kernel_launch(void* const* d_in, const int* in_sizes, int n_in,
                              void* d_out, int out_size, void* d_ws, size_t ws_size,
                              hipStream_t stream) {
    const float* x    = (const float*)d_in[0];
    const int* eidx   = (const int*)d_in[1];
    const int* batch  = (const int*)d_in[2];

    const int N = in_sizes[0] / 128;
    const int E = in_sizes[1] / 2;
    const int G = out_size;

    const int* src = eidx;
    const int* dst = eidx + E;

    const float* cw1[3]; const float* cb1[3]; const float* cg[3]; const float* cbe[3];
    const float* cm[3];  const float* cv[3];  const float* cw2[3]; const float* cb2[3];
    for (int i = 0; i < 3; ++i) {
        int b = 3 + i * 8;
        cw1[i] = (const float*)d_in[b + 0];
        cb1[i] = (const float*)d_in[b + 1];
        cg[i]  = (const float*)d_in[b + 2];
        cbe[i] = (const float*)d_in[b + 3];
        cm[i]  = (const float*)d_in[b + 4];
        cv[i]  = (const float*)d_in[b + 5];
        cw2[i] = (const float*)d_in[b + 6];
        cb2[i] = (const float*)d_in[b + 7];
    }
    const float* l0_w  = (const float*)d_in[27];
    const float* l0_b  = (const float*)d_in[28];
    const float* l0_g  = (const float*)d_in[29];
    const float* l0_be = (const float*)d_in[30];
    const float* l0_m  = (const float*)d_in[31];
    const float* l0_v  = (const float*)d_in[32];
    const float* l1_w  = (const float*)d_in[33];
    const float* l1_b  = (const float*)d_in[34];

    float* outp = (float*)d_out;

    // ---- workspace layout ----
    const int nrb  = (N + 127) / 128;
    const int Npad = nrb * 128;
    const size_t SB = (size_t)Npad * 256 * 2;
    const size_t XB = (size_t)Npad * 128 * 2;
    const size_t PB = (size_t)G * 256 * 4;
    const size_t WTB = (size_t)256 * 256 * 2;

    char* ws = (char*)d_ws;
    size_t o = 0;
    __hip_bfloat16* U  = (__hip_bfloat16*)(ws + o); o += SB;
    __hip_bfloat16* V  = (__hip_bfloat16*)(ws + o); o += SB;
    __hip_bfloat16* xb = (__hip_bfloat16*)(ws + o); o += XB;
    float* pooled      = (float*)(ws + o);       o += PB;
    __hip_bfloat16* wt[6];
    for (int i = 0; i < 6; ++i) { wt[i] = (__hip_bfloat16*)(ws + o); o += WTB; }
    float* ss          = (float*)(ws + o);       o += 6 * 512 * 4;
    int* csr_off    = (int*)(ws + o); o += (size_t)(N + 1) * 4;
    int* cursor     = (int*)(ws + o); o += (size_t)N * 4;
    int* sorted_src = (int*)(ws + o); o += (size_t)E * 4;
    int* sums       = (int*)(ws + o); o += 256 * 4;
    if (ws_size < o) return;

    const dim3 blk(256);

    // ---- prep (pooled memset early; consumed by L2's fused pooling) ----
    hipMemsetAsync(pooled, 0, PB, stream);
    {
        int total4 = Npad * 128 / 4;
        cvt_x_kernel<<<(total4 + 255) / 256, blk, 0, stream>>>(x, xb, N, total4);
    }
    {
        int total = 256 * 128 + 5 * 256 * 256;
        wt_all_kernel<<<(total + 255) / 256, blk, 0, stream>>>(
            cw1[0], cw2[0], cw1[1], cw2[1], cw1[2], cw2[2],
            wt[0], wt[1], wt[2], wt[3], wt[4], wt[5]);
    }
    prep_ss_kernel<<<3, blk, 0, stream>>>(
        cg[0], cbe[0], cm[0], cv[0], cb1[0], cb2[0],
        cg[1], cbe[1], cm[1], cv[1], cb1[1], cb2[1],
        cg[2], cbe[2], cm[2], cv[2], cb1[2], cb2[2], ss);

    // ---- CSR build ----
    {
        const int n_off = N + 1;
        hipMemsetAsync(csr_off, 0, (size_t)n_off * sizeof(int), stream);
        hist_kernel<<<(E + 255) / 256, blk, 0, stream>>>(dst, csr_off, E);
        const int nb = (n_off + 1023) / 1024;
        scan1_kernel<<<nb, blk, 0, stream>>>(csr_off, sums, n_off);
        scan2_kernel<<<1, blk, 0, stream>>>(sums, nb);
        scan3_kernel<<<(n_off + 255) / 256, blk, 0, stream>>>(csr_off, sums, cursor, n_off, N);
        fill_kernel<<<(E + 255) / 256, blk, 0, stream>>>(src, dst, cursor, sorted_src, E);
    }

    auto SS = [&](int i) { return ss + i * 512; };

    // ---------------- layer 0 (128 -> 256): agg xb->U, mlp U->V ----
    {
        int total = N * 16;
        agg_fused<128><<<(total + 255) / 256, blk, 0, stream>>>(xb, csr_off, sorted_src, U, N);
    }
    mlp_fused<128, false><<<nrb, dim3(512), 0, stream>>>(
        U, wt[0], wt[1], SS(0), SS(1), V, nullptr, nullptr, N);

    // ---------------- layer 1: agg V->U, mlp U->U (in-place) ----
    {
        int total = N * 32;
        agg_fused<256><<<(total + 255) / 256, blk, 0, stream>>>(V, csr_off, sorted_src, U, N);
    }
    mlp_fused<256, false><<<nrb, dim3(512), 0, stream>>>(
        U, wt[2], wt[3], SS(2), SS(3), U, nullptr, nullptr, N);

    // ---------------- layer 2: agg U->V, mlp V->pooled (fused pooling) ----
    {
        int total = N * 32;
        agg_fused<256><<<(total + 255) / 256, blk, 0, stream>>>(U, csr_off, sorted_src, V, N);
    }
    mlp_fused<256, true><<<nrb, dim3(512), 0, stream>>>(
        V, wt[4], wt[5], SS(4), SS(5), nullptr, batch, pooled, N);

    // ---------------- head ----------------
    head_kernel<<<G, dim3(128), 0, stream>>>(pooled, l0_w, l0_b, l0_g, l0_be, l0_m, l0_v,
                                             l1_w, l1_b, outp);
}

// Round 17
// 395.135 us; speedup vs baseline: 1.0246x; 1.0246x over previous
//
#include <hip/hip_runtime.h>
#include <hip/hip_bf16.h>

#define BN_EPS 1e-5f

typedef __attribute__((ext_vector_type(8))) short short8;
typedef __attribute__((ext_vector_type(4))) float f32x4;

__device__ __forceinline__ void gll16(const void* g, void* l) {
    __builtin_amdgcn_global_load_lds(
        (const __attribute__((address_space(1))) unsigned int*)g,
        (__attribute__((address_space(3))) unsigned int*)l, 16, 0, 0);
}

__device__ __forceinline__ unsigned pack_bf2(float a, float b) {
    __hip_bfloat16 ba = __float2bfloat16(a);
    __hip_bfloat16 bb = __float2bfloat16(b);
    return (unsigned)(*(unsigned short*)&ba) | ((unsigned)(*(unsigned short*)&bb) << 16);
}

// ===========================================================================
// CSR construction (graph identical across the 3 layers)
// ===========================================================================
__global__ void hist_kernel(const int* __restrict__ dst, int* __restrict__ off, int E) {
    int e = blockIdx.x * blockDim.x + threadIdx.x;
    if (e < E) atomicAdd(&off[dst[e] + 1], 1);
}

__global__ __launch_bounds__(256) void scan1_kernel(int* __restrict__ data,
                                                    int* __restrict__ sums, int n) {
    __shared__ int sh[256];
    const int t = threadIdx.x;
    const int idx = blockIdx.x * 1024 + t * 4;
    int v[4];
    int s = 0;
#pragma unroll
    for (int j = 0; j < 4; ++j) {
        int x = (idx + j < n) ? data[idx + j] : 0;
        s += x;
        v[j] = s;
    }
    sh[t] = s;
    __syncthreads();
    for (int o = 1; o < 256; o <<= 1) {
        int x = (t >= o) ? sh[t - o] : 0;
        __syncthreads();
        sh[t] += x;
        __syncthreads();
    }
    const int prev = sh[t] - s;
#pragma unroll
    for (int j = 0; j < 4; ++j) {
        if (idx + j < n) data[idx + j] = v[j] + prev;
    }
    if (t == 255) sums[blockIdx.x] = sh[255];
}

__global__ __launch_bounds__(256) void scan2_kernel(int* __restrict__ sums, int nb) {
    __shared__ int sh[256];
    const int t = threadIdx.x;
    sh[t] = (t < nb) ? sums[t] : 0;
    __syncthreads();
    for (int o = 1; o < 256; o <<= 1) {
        int x = (t >= o) ? sh[t - o] : 0;
        __syncthreads();
        sh[t] += x;
        __syncthreads();
    }
    if (t < nb) sums[t] = sh[t];
}

__global__ void scan3_kernel(int* __restrict__ data, const int* __restrict__ sums,
                             int* __restrict__ cursor, int n, int N) {
    int i = blockIdx.x * blockDim.x + threadIdx.x;
    if (i >= n) return;
    int b = i >> 10;
    int v = data[i];
    if (b > 0) { v += sums[b - 1]; data[i] = v; }
    if (i < N) cursor[i] = v;
}

__global__ void fill_kernel(const int* __restrict__ src, const int* __restrict__ dst,
                            int* __restrict__ cursor, int* __restrict__ sorted_src, int E) {
    int e = blockIdx.x * blockDim.x + threadIdx.x;
    if (e >= E) return;
    int p = atomicAdd(&cursor[dst[e]], 1);
    sorted_src[p] = src[e];
}

// ===========================================================================
// prep kernels
// ===========================================================================
__global__ void cvt_x_kernel(const float* __restrict__ x, __hip_bfloat16* __restrict__ xb,
                             int N, int total4 /* Npad*128/4 */) {
    int i = blockIdx.x * blockDim.x + threadIdx.x;
    if (i >= total4) return;
    int n = i >> 5;
    unsigned lo = 0, hi = 0;
    if (n < N) {
        const float4 v = ((const float4*)x)[i];
        lo = pack_bf2(v.x, v.y);
        hi = pack_bf2(v.z, v.w);
    }
    ((uint2*)xb)[i] = make_uint2(lo, hi);
}

__global__ void wt_all_kernel(const float* __restrict__ w0, const float* __restrict__ w1,
                              const float* __restrict__ w2, const float* __restrict__ w3,
                              const float* __restrict__ w4, const float* __restrict__ w5,
                              __hip_bfloat16* __restrict__ o0, __hip_bfloat16* __restrict__ o1,
                              __hip_bfloat16* __restrict__ o2, __hip_bfloat16* __restrict__ o3,
                              __hip_bfloat16* __restrict__ o4, __hip_bfloat16* __restrict__ o5) {
    int i = blockIdx.x * blockDim.x + threadIdx.x;
    const int S0 = 256 * 128, S = 256 * 256;
    if (i < S0) {
        int m = i / 128, k = i - m * 128;
        o0[i] = __float2bfloat16(w0[k * 256 + m]);
        return;
    }
    i -= S0;
    int mi = i / S, j = i - mi * S;
    if (mi >= 5) return;
    int m = j >> 8, k = j & 255;
    const float* Wp; __hip_bfloat16* Op;
    switch (mi) {
        case 0: Wp = w1; Op = o1; break;
        case 1: Wp = w2; Op = o2; break;
        case 2: Wp = w3; Op = o3; break;
        case 3: Wp = w4; Op = o4; break;
        default: Wp = w5; Op = o5; break;
    }
    Op[j] = __float2bfloat16(Wp[k * 256 + m]);
}

__global__ void prep_ss_kernel(
    const float* __restrict__ g0, const float* __restrict__ be0, const float* __restrict__ m0,
    const float* __restrict__ v0, const float* __restrict__ b10, const float* __restrict__ b20,
    const float* __restrict__ g1, const float* __restrict__ be1, const float* __restrict__ m1,
    const float* __restrict__ v1, const float* __restrict__ b11, const float* __restrict__ b21,
    const float* __restrict__ g2, const float* __restrict__ be2, const float* __restrict__ m2,
    const float* __restrict__ v2, const float* __restrict__ b12, const float* __restrict__ b22,
    float* __restrict__ ss) {
    const int layer = blockIdx.x;
    const int c = threadIdx.x;
    const float *g, *be, *m, *v, *b1, *b2;
    switch (layer) {
        case 0: g = g0; be = be0; m = m0; v = v0; b1 = b10; b2 = b20; break;
        case 1: g = g1; be = be1; m = m1; v = v1; b1 = b11; b2 = b21; break;
        default: g = g2; be = be2; m = m2; v = v2; b1 = b12; b2 = b22; break;
    }
    float r = rsqrtf(v[c] + BN_EPS);
    float s = g[c] * r;
    ss[(2 * layer) * 512 + c] = s;
    ss[(2 * layer) * 512 + 256 + c] = (b1[c] - m[c]) * s + be[c];
    ss[(2 * layer + 1) * 512 + c] = 1.f;
    ss[(2 * layer + 1) * 512 + 256 + c] = b2[c];
}

// ===========================================================================
// fused aggregate: out[n] = h[n] + sum_{e in CSR(n)} h[src[e]]  (bf16 in/out)
// 4-deep edge unroll: more gather loads in flight per wave.
// ===========================================================================
template <int C>
__global__ __launch_bounds__(256) void agg_fused(const __hip_bfloat16* __restrict__ h,
                                                 const int* __restrict__ off,
                                                 const int* __restrict__ ssrc,
                                                 __hip_bfloat16* __restrict__ out, int N) {
    constexpr int L = C / 8;
    int t = blockIdx.x * blockDim.x + threadIdx.x;
    int n = t / L;
    if (n >= N) return;
    int c8 = t - n * L;
    const uint4* hp = (const uint4*)h;

    float acc[8];
    {
        uint4 sv = hp[(size_t)n * L + c8];
        const unsigned u[4] = {sv.x, sv.y, sv.z, sv.w};
#pragma unroll
        for (int j = 0; j < 4; ++j) {
            acc[2 * j]     = __uint_as_float(u[j] << 16);
            acc[2 * j + 1] = __uint_as_float(u[j] & 0xffff0000u);
        }
    }
    const int e0 = off[n], e1 = off[n + 1];
    int e = e0;
    for (; e + 4 <= e1; e += 4) {
        int s0 = ssrc[e], s1 = ssrc[e + 1], s2 = ssrc[e + 2], s3 = ssrc[e + 3];
        uint4 a = hp[(size_t)s0 * L + c8];
        uint4 b = hp[(size_t)s1 * L + c8];
        uint4 cc = hp[(size_t)s2 * L + c8];
        uint4 d = hp[(size_t)s3 * L + c8];
        const unsigned ua[4] = {a.x, a.y, a.z, a.w};
        const unsigned ub[4] = {b.x, b.y, b.z, b.w};
        const unsigned uc[4] = {cc.x, cc.y, cc.z, cc.w};
        const unsigned ud[4] = {d.x, d.y, d.z, d.w};
#pragma unroll
        for (int j = 0; j < 4; ++j) {
            acc[2 * j]     += __uint_as_float(ua[j] << 16) + __uint_as_float(ub[j] << 16) +
                              __uint_as_float(uc[j] << 16) + __uint_as_float(ud[j] << 16);
            acc[2 * j + 1] += __uint_as_float(ua[j] & 0xffff0000u) + __uint_as_float(ub[j] & 0xffff0000u) +
                              __uint_as_float(uc[j] & 0xffff0000u) + __uint_as_float(ud[j] & 0xffff0000u);
        }
    }
    for (; e + 2 <= e1; e += 2) {
        int s0 = ssrc[e], s1 = ssrc[e + 1];
        uint4 a = hp[(size_t)s0 * L + c8];
        uint4 b = hp[(size_t)s1 * L + c8];
        const unsigned ua[4] = {a.x, a.y, a.z, a.w};
        const unsigned ub[4] = {b.x, b.y, b.z, b.w};
#pragma unroll
        for (int j = 0; j < 4; ++j) {
            acc[2 * j]     += __uint_as_float(ua[j] << 16) + __uint_as_float(ub[j] << 16);
            acc[2 * j + 1] += __uint_as_float(ua[j] & 0xffff0000u) + __uint_as_float(ub[j] & 0xffff0000u);
        }
    }
    if (e < e1) {
        int s0 = ssrc[e];
        uint4 a = hp[(size_t)s0 * L + c8];
        const unsigned ua[4] = {a.x, a.y, a.z, a.w};
#pragma unroll
        for (int j = 0; j < 4; ++j) {
            acc[2 * j]     += __uint_as_float(ua[j] << 16);
            acc[2 * j + 1] += __uint_as_float(ua[j] & 0xffff0000u);
        }
    }
    unsigned o[4];
#pragma unroll
    for (int j = 0; j < 4; ++j) o[j] = pack_bf2(acc[2 * j], acc[2 * j + 1]);
    ((uint4*)out)[(size_t)n * L + c8] = make_uint4(o[0], o[1], o[2], o[3]);
}

// ===========================================================================
// fused MLP layer (r12/r15 structure, proven best): 128-row panel x 256 cols,
// 8 waves. Frag-order 64KB LDS (conflict-clean), 2-deep W register pipeline.
// POOL=true (last layer): in-LDS segmented pooling + atomics. r16 lesson:
// the pool path's scalar u16 reads had c / c+8 / c+16 / c+32 in the SAME
// bank (cbase strides 256/512/1024B) -> 16-way conflict (3.2M). Fix: rotate
// the row-visit order per lane (row (ii + lane>>2) & 15) so the 64 lanes
// touch 16 different 16B slots each step. AtomicAdd-segmented accumulation
// is order-independent, so rotation is safe (<=1 extra flush per group).
// ===========================================================================
template <int K1, bool POOL>
__global__ __launch_bounds__(512, 4) void mlp_fused(
    const __hip_bfloat16* __restrict__ A,
    const __hip_bfloat16* __restrict__ W1t,   // [256][K1] bf16 (W1 transposed)
    const __hip_bfloat16* __restrict__ W2t,   // [256][256] bf16
    const float* __restrict__ ss1, const float* __restrict__ ss2,
    __hip_bfloat16* __restrict__ C,
    const int* __restrict__ batch, float* __restrict__ pooled, int N) {
    __shared__ __align__(16) char bufT[64 * 1024];
    __shared__ int batch_sh[128];

    const int tid = threadIdx.x;
    const int l   = tid & 63;
    const int w   = tid >> 6;        // wave 0..7 -> cols w*32..+31
    const int l15 = l & 15;
    const int kg  = l >> 4;          // k-octet group 0..3
    const size_t row0 = (size_t)blockIdx.x * 128;

    constexpr int ROWB = K1 * 2;
    constexpr int NT1  = K1 / 32;

    const char* W1base = (const char*)W1t + (size_t)(w * 32 + l15) * ROWB + kg * 16;
    const char* W2base = (const char*)W2t + (size_t)(w * 32 + l15) * 512 + kg * 16;

    // ---- W1 tile 0 -> regs (latency hides under A staging) ----
    short8 wc0 = *(const short8*)(W1base);
    short8 wc1 = *(const short8*)(W1base + 16 * ROWB);

    // ---- stage A panel in fragment order ----
    {
        const char* Ab = (const char*)(A + row0 * K1);
#pragma unroll
        for (int ib = w; ib < 8 * NT1; ib += 8) {
            const int j = ib / NT1, t = ib % NT1;
            gll16(Ab + (size_t)(j * 16 + l15) * ROWB + t * 64 + kg * 16,
                  bufT + ib * 1024);
        }
    }
    asm volatile("s_waitcnt vmcnt(0)" ::: "memory");
    __syncthreads();

    f32x4 acc[2][8];
#pragma unroll
    for (int i = 0; i < 2; ++i)
#pragma unroll
        for (int j = 0; j < 8; ++j) acc[i][j] = (f32x4){0.f, 0.f, 0.f, 0.f};

    // ================= GEMM1: T = A @ W1 (W reg-pipelined) =================
    {
        auto step = [&](int t, short8 wa, short8 wb) {
#pragma unroll
            for (int jh = 0; jh < 2; ++jh) {
                short8 af[4];
#pragma unroll
                for (int jj = 0; jj < 4; ++jj)
                    af[jj] = *(const short8*)(bufT + ((jh * 4 + jj) * NT1 + t) * 1024 + l * 16);
#pragma unroll
                for (int jj = 0; jj < 4; ++jj) {
                    acc[0][jh * 4 + jj] = __builtin_amdgcn_mfma_f32_16x16x32_bf16(
                        wa, af[jj], acc[0][jh * 4 + jj], 0, 0, 0);
                    acc[1][jh * 4 + jj] = __builtin_amdgcn_mfma_f32_16x16x32_bf16(
                        wb, af[jj], acc[1][jh * 4 + jj], 0, 0, 0);
                }
            }
        };
#pragma unroll 1
        for (int t = 0; t < NT1 - 1; ++t) {
            short8 wn0 = *(const short8*)(W1base + (t + 1) * 64);
            short8 wn1 = *(const short8*)(W1base + 16 * ROWB + (t + 1) * 64);
            step(t, wc0, wc1);
            wc0 = wn0; wc1 = wn1;
        }
        step(NT1 - 1, wc0, wc1);
    }
    __syncthreads();

    // ---- W2 tile 0 -> regs ----
    wc0 = *(const short8*)(W2base);
    wc1 = *(const short8*)(W2base + 16 * 512);

    // ---- T epilogue: bn+relu, fragment-order packed 8B writes ----
#pragma unroll
    for (int i = 0; i < 2; ++i) {
        const int m0 = w * 32 + i * 16 + kg * 4;
        const float4 s4 = *(const float4*)(ss1 + m0);
        const float4 h4 = *(const float4*)(ss1 + 256 + m0);
        const int toff = w * 1024 + (i * 2 + (kg >> 1)) * 256 + l15 * 16 + (kg & 1) * 8;
#pragma unroll
        for (int j = 0; j < 8; ++j) {
            const float v0 = fmaxf(acc[i][j][0] * s4.x + h4.x, 0.f);
            const float v1 = fmaxf(acc[i][j][1] * s4.y + h4.y, 0.f);
            const float v2 = fmaxf(acc[i][j][2] * s4.z + h4.z, 0.f);
            const float v3 = fmaxf(acc[i][j][3] * s4.w + h4.w, 0.f);
            *(uint2*)(bufT + j * 8192 + toff) = make_uint2(pack_bf2(v0, v1), pack_bf2(v2, v3));
        }
    }
    __syncthreads();

#pragma unroll
    for (int i = 0; i < 2; ++i)
#pragma unroll
        for (int j = 0; j < 8; ++j) acc[i][j] = (f32x4){0.f, 0.f, 0.f, 0.f};

    // ================= GEMM2: C = T @ W2 (W reg-pipelined) =================
    {
        auto step = [&](int t, short8 wa, short8 wb) {
#pragma unroll
            for (int jh = 0; jh < 2; ++jh) {
                short8 tf[4];
#pragma unroll
                for (int jj = 0; jj < 4; ++jj)
                    tf[jj] = *(const short8*)(bufT + ((jh * 4 + jj) * 8 + t) * 1024 + l * 16);
#pragma unroll
                for (int jj = 0; jj < 4; ++jj) {
                    acc[0][jh * 4 + jj] = __builtin_amdgcn_mfma_f32_16x16x32_bf16(
                        wa, tf[jj], acc[0][jh * 4 + jj], 0, 0, 0);
                    acc[1][jh * 4 + jj] = __builtin_amdgcn_mfma_f32_16x16x32_bf16(
                        wb, tf[jj], acc[1][jh * 4 + jj], 0, 0, 0);
                }
            }
        };
#pragma unroll 1
        for (int t = 0; t < 7; ++t) {
            short8 wn0 = *(const short8*)(W2base + (t + 1) * 64);
            short8 wn1 = *(const short8*)(W2base + 16 * 512 + (t + 1) * 64);
            step(t, wc0, wc1);
            wc0 = wn0; wc1 = wn1;
        }
        step(7, wc0, wc1);
    }
    __syncthreads();

    // ---- C epilogue into LDS (fragment order) ----
#pragma unroll
    for (int i = 0; i < 2; ++i) {
        const int c0 = w * 32 + i * 16 + kg * 4;
        const float4 s4 = *(const float4*)(ss2 + c0);
        const float4 h4 = *(const float4*)(ss2 + 256 + c0);
        const int toff = w * 1024 + (i * 2 + (kg >> 1)) * 256 + l15 * 16 + (kg & 1) * 8;
#pragma unroll
        for (int j = 0; j < 8; ++j) {
            const float v0 = fmaxf(acc[i][j][0] * s4.x + h4.x, 0.f);
            const float v1 = fmaxf(acc[i][j][1] * s4.y + h4.y, 0.f);
            const float v2 = fmaxf(acc[i][j][2] * s4.z + h4.z, 0.f);
            const float v3 = fmaxf(acc[i][j][3] * s4.w + h4.w, 0.f);
            *(uint2*)(bufT + j * 8192 + toff) = make_uint2(pack_bf2(v0, v1), pack_bf2(v2, v3));
        }
    }
    if (POOL && tid < 128) {
        const int r = (int)row0 + tid;
        batch_sh[tid] = (r < N) ? batch[r] : -1;
    }
    __syncthreads();

    if (!POOL) {
        char* Cb = (char*)C + row0 * 512;
#pragma unroll
        for (int q = tid; q < 4096; q += 512) {
            const int j  = q >> 9;
            const int wp = (q >> 6) & 7;
            const int lp = q & 63;
            uint4 v = *(const uint4*)(bufT + q * 16);
            *(uint4*)(Cb + (size_t)(j * 16 + (lp & 15)) * 512 + wp * 64 + (lp >> 4) * 16) = v;
        }
    } else {
        // ---- in-LDS segmented pooling, rotated row order (bank-spread) ----
        const int c   = tid & 255;
        const int rh  = tid >> 8;          // 0 or 1: rows rh*64..+63
        const int rot = (tid >> 2) & 15;   // per-lane rotation
        const int cbase = (c >> 5) * 1024 +
                          (((c >> 4) & 1) * 2 + ((c >> 3) & 1)) * 256 +
                          ((c >> 2) & 1) * 8 + (c & 3) * 2;
        float accp = 0.f;
        int gprev = -1;
#pragma unroll 1
        for (int grp = 0; grp < 4; ++grp) {
            const int base = rh * 64 + grp * 16;
            const char* bb = bufT + ((base >> 4)) * 8192 + cbase;
#pragma unroll
            for (int ii = 0; ii < 16; ++ii) {
                const int rr = (ii + rot) & 15;       // rotated row-in-group
                const int g = batch_sh[base + rr];
                if (g < 0) continue;                  // padded tail
                if (g != gprev) {
                    if (gprev >= 0) atomicAdd(&pooled[(size_t)gprev * 256 + c], accp);
                    accp = 0.f;
                    gprev = g;
                }
                const unsigned short* p = (const unsigned short*)(bb + rr * 16);
                accp += __uint_as_float(((unsigned)*p) << 16);
            }
        }
        if (gprev >= 0) atomicAdd(&pooled[(size_t)gprev * 256 + c], accp);
    }
}

// ===========================================================================
// head: out[g] = relu(bn(pooled[g]@w0 + b0)) @ w1 + b1
// ===========================================================================
__global__ __launch_bounds__(128) void head_kernel(
    const float* __restrict__ pooled,
    const float* __restrict__ w0, const float* __restrict__ b0,
    const float* __restrict__ g, const float* __restrict__ be,
    const float* __restrict__ m, const float* __restrict__ v,
    const float* __restrict__ w1, const float* __restrict__ b1,
    float* __restrict__ out) {
    __shared__ float row[256];
    __shared__ float red[128];
    const int gid = blockIdx.x;
    const int j = threadIdx.x;

    row[j]       = pooled[(size_t)gid * 256 + j];
    row[j + 128] = pooled[(size_t)gid * 256 + 128 + j];
    __syncthreads();

    float acc = b0[j];
#pragma unroll 8
    for (int k = 0; k < 256; ++k) acc += row[k] * w0[k * 128 + j];

    float h = g[j] * (acc - m[j]) * rsqrtf(v[j] + BN_EPS) + be[j];
    h = fmaxf(h, 0.f) * w1[j];
    red[j] = h;
    __syncthreads();
    for (int s = 64; s > 0; s >>= 1) {
        if (j < s) red[j] += red[j + s];
        __syncthreads();
    }
    if (j == 0) out[gid] = red[0] + b1[0];
}

// ===========================================================================
// launch
// ===========================================================================
extern "C" void kernel_launch(void* const* d_in, const int* in_sizes, int n_in,
                              void* d_out, int out_size, void* d_ws, size_t ws_size,
                              hipStream_t stream) {
    const float* x    = (const float*)d_in[0];
    const int* eidx   = (const int*)d_in[1];
    const int* batch  = (const int*)d_in[2];

    const int N = in_sizes[0] / 128;
    const int E = in_sizes[1] / 2;
    const int G = out_size;

    const int* src = eidx;
    const int* dst = eidx + E;

    const float* cw1[3]; const float* cb1[3]; const float* cg[3]; const float* cbe[3];
    const float* cm[3];  const float* cv[3];  const float* cw2[3]; const float* cb2[3];
    for (int i = 0; i < 3; ++i) {
        int b = 3 + i * 8;
        cw1[i] = (const float*)d_in[b + 0];
        cb1[i] = (const float*)d_in[b + 1];
        cg[i]  = (const float*)d_in[b + 2];
        cbe[i] = (const float*)d_in[b + 3];
        cm[i]  = (const float*)d_in[b + 4];
        cv[i]  = (const float*)d_in[b + 5];
        cw2[i] = (const float*)d_in[b + 6];
        cb2[i] = (const float*)d_in[b + 7];
    }
    const float* l0_w  = (const float*)d_in[27];
    const float* l0_b  = (const float*)d_in[28];
    const float* l0_g  = (const float*)d_in[29];
    const float* l0_be = (const float*)d_in[30];
    const float* l0_m  = (const float*)d_in[31];
    const float* l0_v  = (const float*)d_in[32];
    const float* l1_w  = (const float*)d_in[33];
    const float* l1_b  = (const float*)d_in[34];

    float* outp = (float*)d_out;

    // ---- workspace layout ----
    const int nrb  = (N + 127) / 128;
    const int Npad = nrb * 128;
    const size_t SB = (size_t)Npad * 256 * 2;
    const size_t XB = (size_t)Npad * 128 * 2;
    const size_t PB = (size_t)G * 256 * 4;
    const size_t WTB = (size_t)256 * 256 * 2;

    char* ws = (char*)d_ws;
    size_t o = 0;
    __hip_bfloat16* U  = (__hip_bfloat16*)(ws + o); o += SB;
    __hip_bfloat16* V  = (__hip_bfloat16*)(ws + o); o += SB;
    __hip_bfloat16* xb = (__hip_bfloat16*)(ws + o); o += XB;
    float* pooled      = (float*)(ws + o);       o += PB;
    __hip_bfloat16* wt[6];
    for (int i = 0; i < 6; ++i) { wt[i] = (__hip_bfloat16*)(ws + o); o += WTB; }
    float* ss          = (float*)(ws + o);       o += 6 * 512 * 4;
    int* csr_off    = (int*)(ws + o); o += (size_t)(N + 1) * 4;
    int* cursor     = (int*)(ws + o); o += (size_t)N * 4;
    int* sorted_src = (int*)(ws + o); o += (size_t)E * 4;
    int* sums       = (int*)(ws + o); o += 256 * 4;
    if (ws_size < o) return;

    const dim3 blk(256);

    // ---- prep (pooled memset early; consumed by L2's fused pooling) ----
    hipMemsetAsync(pooled, 0, PB, stream);
    {
        int total4 = Npad * 128 / 4;
        cvt_x_kernel<<<(total4 + 255) / 256, blk, 0, stream>>>(x, xb, N, total4);
    }
    {
        int total = 256 * 128 + 5 * 256 * 256;
        wt_all_kernel<<<(total + 255) / 256, blk, 0, stream>>>(
            cw1[0], cw2[0], cw1[1], cw2[1], cw1[2], cw2[2],
            wt[0], wt[1], wt[2], wt[3], wt[4], wt[5]);
    }
    prep_ss_kernel<<<3, blk, 0, stream>>>(
        cg[0], cbe[0], cm[0], cv[0], cb1[0], cb2[0],
        cg[1], cbe[1], cm[1], cv[1], cb1[1], cb2[1],
        cg[2], cbe[2], cm[2], cv[2], cb1[2], cb2[2], ss);

    // ---- CSR build ----
    {
        const int n_off = N + 1;
        hipMemsetAsync(csr_off, 0, (size_t)n_off * sizeof(int), stream);
        hist_kernel<<<(E + 255) / 256, blk, 0, stream>>>(dst, csr_off, E);
        const int nb = (n_off + 1023) / 1024;
        scan1_kernel<<<nb, blk, 0, stream>>>(csr_off, sums, n_off);
        scan2_kernel<<<1, blk, 0, stream>>>(sums, nb);
        scan3_kernel<<<(n_off + 255) / 256, blk, 0, stream>>>(csr_off, sums, cursor, n_off, N);
        fill_kernel<<<(E + 255) / 256, blk, 0, stream>>>(src, dst, cursor, sorted_src, E);
    }

    auto SS = [&](int i) { return ss + i * 512; };

    // ---------------- layer 0 (128 -> 256): agg xb->U, mlp U->V ----
    {
        int total = N * 16;
        agg_fused<128><<<(total + 255) / 256, blk, 0, stream>>>(xb, csr_off, sorted_src, U, N);
    }
    mlp_fused<128, false><<<nrb, dim3(512), 0, stream>>>(
        U, wt[0], wt[1], SS(0), SS(1), V, nullptr, nullptr, N);

    // ---------------- layer 1: agg V->U, mlp U->U (in-place) ----
    {
        int total = N * 32;
        agg_fused<256><<<(total + 255) / 256, blk, 0, stream>>>(V, csr_off, sorted_src, U, N);
    }
    mlp_fused<256, false><<<nrb, dim3(512), 0, stream>>>(
        U, wt[2], wt[3], SS(2), SS(3), U, nullptr, nullptr, N);

    // ---------------- layer 2: agg U->V, mlp V->pooled (fused pooling) ----
    {
        int total = N * 32;
        agg_fused<256><<<(total + 255) / 256, blk, 0, stream>>>(U, csr_off, sorted_src, V, N);
    }
    mlp_fused<256, true><<<nrb, dim3(512), 0, stream>>>(
        V, wt[4], wt[5], SS(4), SS(5), nullptr, batch, pooled, N);

    // ---------------- head ----------------
    head_kernel<<<G, dim3(128), 0, stream>>>(pooled, l0_w, l0_b, l0_g, l0_be, l0_m, l0_v,
                                             l1_w, l1_b, outp);
}